// Round 6
// baseline (1752.148 us; speedup 1.0000x reference)
//
#include <hip/hip_runtime.h>

#define D 64
#define BSHIFT 7              // 128 nodes per dst bucket
#define BNODES (1 << BSHIFT)
#define SUBSH 10              // 1024-edge capacity per (bucket, srctile) region; E[region]=292
#define NBK2_MAX 6400         // bucket*8 regions; supports N <= 102400

typedef __attribute__((ext_vector_type(8))) short bf16x8;
typedef __attribute__((ext_vector_type(4))) float f32x4;

// ---------- bf16 helpers (bit-exact RNE pack, shift-based unpack) ----------
__device__ __forceinline__ unsigned int f2bf_rne(float f) {
    unsigned int b = __float_as_uint(f);
    return (b + 0x7fffu + ((b >> 16) & 1u)) >> 16;
}
__device__ __forceinline__ unsigned int pack_bf(float lo, float hi) {
    return f2bf_rne(lo) | (f2bf_rne(hi) << 16);
}
__device__ __forceinline__ float bflo(unsigned int u) { return __uint_as_float(u << 16); }
__device__ __forceinline__ float bfhi(unsigned int u) { return __uint_as_float(u & 0xffff0000u); }

// ---------- cast fp32 features -> packed bf16 (2 feats per uint); also zeroes cnt2 ----------
__global__ void cast_kernel(const float4* __restrict__ xin, uint2* __restrict__ xb, int n4,
                            int* __restrict__ cnt2, int nz) {
    int gid = blockIdx.x * blockDim.x + threadIdx.x;
    if (gid < nz) cnt2[gid] = 0;
    int stride = gridDim.x * blockDim.x;
    for (int i = gid; i < n4; i += stride) {
        float4 v = xin[i];
        uint2 o;
        o.x = pack_bf(v.x, v.y);
        o.y = pack_bf(v.z, v.w);
        xb[i] = o;
    }
}

// ---------- single-pass scatter into (dst-bucket, src-tile) regions ----------
// key = (dst>>7)*8 + (src>>14). Per-block LDS histogram, ONE global atomicAdd per
// (block,key) to reserve a run, then dense scatter of (src | dst_low<<17) records.
// G1=64 blocks keeps ~16-edge runs per (block,region) so writes form 64B bursts.
__global__ __launch_bounds__(512) void binscatter_kernel(
    const int* __restrict__ src, const int* __restrict__ dst,
    int* __restrict__ cnt2, unsigned int* __restrict__ pairs,
    int E, int NBK2, int CE) {
    __shared__ int lh[NBK2_MAX];
    __shared__ int lbase[NBK2_MAX];
    for (int k = threadIdx.x; k < NBK2; k += 512) lh[k] = 0;
    __syncthreads();
    int b = blockIdx.x;
    int beg = b * CE, end = min(beg + CE, E);
    for (int e = beg + threadIdx.x; e < end; e += 512) {
        int k = ((dst[e] >> BSHIFT) << 3) | (src[e] >> 14);
        atomicAdd(&lh[k], 1);
    }
    __syncthreads();
    for (int k = threadIdx.x; k < NBK2; k += 512) {
        int c = lh[k];
        if (c) lbase[k] = (k << SUBSH) + atomicAdd(&cnt2[k], c);
        lh[k] = 0;
    }
    __syncthreads();
    for (int e = beg + threadIdx.x; e < end; e += 512) {
        int d = dst[e];
        int s = src[e];
        int k = ((d >> BSHIFT) << 3) | (s >> 14);
        int r = atomicAdd(&lh[k], 1);
        pairs[lbase[k] + r] = (unsigned int)s | ((unsigned int)(d & (BNODES - 1)) << 17);
    }
}

// ---------- fused layer v2: edge-streaming LDS-atomic aggregation + MFMA linear ----------
// One block (512 thr = 8 waves) per 128-node dst bucket. No CSR: stream the bucket's
// unsorted (src|dstlocal) records region-by-region (src-tile order; waves 0-3 take even
// regions, 4-7 odd, so co-resident blocks share a 2MB src tile -> XCD-L2 hits).
// 8 lanes/edge, 4 edges per octet in flight; bf16 row unpacked and ds_add_f32'd into
// acc[128][65] f32 (padded stride kills bank aliasing). Then mean -> swizzled bf16 LDS
// tile -> the proven 16x16x32 MFMA phase with hi/lo-split weights (fp32-accurate).
__global__ __launch_bounds__(512) void stream_layer_kernel(
    const unsigned int* __restrict__ xin, const unsigned int* __restrict__ pairs,
    const int* __restrict__ cnt2,
    const float* __restrict__ Wl, const float* __restrict__ Wr,
    const float* __restrict__ bias,
    float* __restrict__ outf, unsigned int* __restrict__ outb, int N, int relu) {
    __shared__ float facc[BNODES][65];
    __shared__ int sdeg[BNODES];
    __shared__ int scnt[8];
    __shared__ uint4 smean[BNODES][8];

    int tid = threadIdx.x;
    int wave = tid >> 6;
    int lane = tid & 63;
    int b = blockIdx.x;
    int node0 = b << BSHIFT;

    for (int i = tid; i < BNODES * 65; i += 512) (&facc[0][0])[i] = 0.f;
    if (tid < BNODES) sdeg[tid] = 0;
    if (tid < 8) scnt[tid] = cnt2[(b << 3) + tid];
    __syncthreads();

    // ---- edge streaming: half-block h handles regions 2t+h ----
    int h    = wave >> 2;               // 0 or 1
    int oct  = (tid >> 3) & 31;         // octet within half: 0..31
    int fl   = tid & 7;                 // uint4 granule within 128B row
    int fl8  = fl * 8;
    for (int t = 0; t < 4; ++t) {
        int rg = t * 2 + h;
        int count = scnt[rg];
        int start = ((b << 3) + rg) << SUBSH;
        for (int c0 = 0; c0 < count; c0 += 128) {
            int sl = c0 + oct * 4;
            uint4 r4 = *(const uint4*)(pairs + start + sl);   // within region (SUBSH pad)
            bool v0 = sl < count, v1 = sl + 1 < count, v2 = sl + 2 < count, v3 = sl + 3 < count;
            int s0 = v0 ? (int)(r4.x & 0x1FFFFu) : 0;
            int s1 = v1 ? (int)(r4.y & 0x1FFFFu) : 0;
            int s2 = v2 ? (int)(r4.z & 0x1FFFFu) : 0;
            int s3 = v3 ? (int)(r4.w & 0x1FFFFu) : 0;
            uint4 u0 = *(const uint4*)(xin + s0 * 32 + fl * 4);
            uint4 u1 = *(const uint4*)(xin + s1 * 32 + fl * 4);
            uint4 u2 = *(const uint4*)(xin + s2 * 32 + fl * 4);
            uint4 u3 = *(const uint4*)(xin + s3 * 32 + fl * 4);
            int d0 = (int)((r4.x >> 17) & 127u);
            int d1 = (int)((r4.y >> 17) & 127u);
            int d2 = (int)((r4.z >> 17) & 127u);
            int d3 = (int)((r4.w >> 17) & 127u);
            uint4 z = make_uint4(0u, 0u, 0u, 0u);
            if (!v0) u0 = z;
            if (!v1) u1 = z;
            if (!v2) u2 = z;
            if (!v3) u3 = z;
            float* a0 = &facc[d0][fl8];
            float* a1 = &facc[d1][fl8];
            float* a2 = &facc[d2][fl8];
            float* a3 = &facc[d3][fl8];
            atomicAdd(a0 + 0, bflo(u0.x)); atomicAdd(a0 + 1, bfhi(u0.x));
            atomicAdd(a0 + 2, bflo(u0.y)); atomicAdd(a0 + 3, bfhi(u0.y));
            atomicAdd(a0 + 4, bflo(u0.z)); atomicAdd(a0 + 5, bfhi(u0.z));
            atomicAdd(a0 + 6, bflo(u0.w)); atomicAdd(a0 + 7, bfhi(u0.w));
            atomicAdd(a1 + 0, bflo(u1.x)); atomicAdd(a1 + 1, bfhi(u1.x));
            atomicAdd(a1 + 2, bflo(u1.y)); atomicAdd(a1 + 3, bfhi(u1.y));
            atomicAdd(a1 + 4, bflo(u1.z)); atomicAdd(a1 + 5, bfhi(u1.z));
            atomicAdd(a1 + 6, bflo(u1.w)); atomicAdd(a1 + 7, bfhi(u1.w));
            atomicAdd(a2 + 0, bflo(u2.x)); atomicAdd(a2 + 1, bfhi(u2.x));
            atomicAdd(a2 + 2, bflo(u2.y)); atomicAdd(a2 + 3, bfhi(u2.y));
            atomicAdd(a2 + 4, bflo(u2.z)); atomicAdd(a2 + 5, bfhi(u2.z));
            atomicAdd(a2 + 6, bflo(u2.w)); atomicAdd(a2 + 7, bfhi(u2.w));
            atomicAdd(a3 + 0, bflo(u3.x)); atomicAdd(a3 + 1, bfhi(u3.x));
            atomicAdd(a3 + 2, bflo(u3.y)); atomicAdd(a3 + 3, bfhi(u3.y));
            atomicAdd(a3 + 4, bflo(u3.z)); atomicAdd(a3 + 5, bfhi(u3.z));
            atomicAdd(a3 + 6, bflo(u3.w)); atomicAdd(a3 + 7, bfhi(u3.w));
            if (fl == 0) {
                atomicAdd(&sdeg[d0], (int)v0); atomicAdd(&sdeg[d1], (int)v1);
                atomicAdd(&sdeg[d2], (int)v2); atomicAdd(&sdeg[d3], (int)v3);
            }
        }
    }
    __syncthreads();

    // ---- weight fragments (global loads overlap the mean-pack LDS work) ----
    int lm   = lane & 15;
    int quad = lane >> 4;
    int ft   = wave & 3;
    int ntb  = (wave >> 2) << 2;        // node-tile base: 0 or 4
    int f_a  = (ft << 4) + lm;
    bf16x8 wh[4], wlo[4];
#pragma unroll
    for (int s = 0; s < 4; ++s) {
        int k8 = s * 32 + quad * 8;
        const float* Wsrc = (k8 < 64) ? Wl : Wr;
        const float* p = Wsrc + f_a * 64 + (k8 & 63);
        float4 w0 = *(const float4*)p;
        float4 w1 = *(const float4*)(p + 4);
        float w[8] = {w0.x, w0.y, w0.z, w0.w, w1.x, w1.y, w1.z, w1.w};
        bf16x8 hh, ll;
#pragma unroll
        for (int jj = 0; jj < 8; ++jj) {
            unsigned int hb = f2bf_rne(w[jj]);
            float hf = __uint_as_float(hb << 16);
            unsigned int lb = f2bf_rne(w[jj] - hf);
            hh[jj] = (short)hb;
            ll[jj] = (short)lb;
        }
        wh[s] = hh;
        wlo[s] = ll;
    }

    // ---- mean-pack: 1024 (node,granule) slots, 2 per thread, swizzled bf16 tile ----
#pragma unroll
    for (int k = 0; k < 2; ++k) {
        int s = tid + k * 512;
        int nl = s >> 3, g = s & 7;
        float inv = 1.0f / fmaxf((float)sdeg[nl], 1.0f);
        const float* ar = &facc[nl][g * 8];
        uint4 ov;
        ov.x = pack_bf(ar[0] * inv, ar[1] * inv);
        ov.y = pack_bf(ar[2] * inv, ar[3] * inv);
        ov.z = pack_bf(ar[4] * inv, ar[5] * inv);
        ov.w = pack_bf(ar[6] * inv, ar[7] * inv);
        smean[nl][g ^ (nl & 7)] = ov;
    }
    __syncthreads();

    // ---- MFMA phase: wave w does f-tile (w&3) over node-tiles ntb..ntb+3 ----
    f32x4 acc4[4];
#pragma unroll
    for (int t = 0; t < 4; ++t) acc4[t] = (f32x4){0.f, 0.f, 0.f, 0.f};

#pragma unroll
    for (int t = 0; t < 4; ++t) {
        int nl = (ntb + t) * 16 + lm;
        int node = node0 + nl;
        bool v = node < N;
        const unsigned int* xrow = xin + (long long)node * 32;
#pragma unroll
        for (int s = 0; s < 2; ++s) {            // mean fragments from LDS
            union { uint4 u4; bf16x8 v8; } cv;
            cv.u4 = smean[nl][(s * 4 + quad) ^ (nl & 7)];
            acc4[t] = __builtin_amdgcn_mfma_f32_16x16x32_bf16(wh[s],  cv.v8, acc4[t], 0, 0, 0);
            acc4[t] = __builtin_amdgcn_mfma_f32_16x16x32_bf16(wlo[s], cv.v8, acc4[t], 0, 0, 0);
        }
#pragma unroll
        for (int s = 2; s < 4; ++s) {            // self fragments from global
            uint4 u = make_uint4(0u, 0u, 0u, 0u);
            if (v) u = *(const uint4*)(xrow + ((s & 1) << 4) + (quad << 2));
            union { uint4 u4; bf16x8 v8; } cv;
            cv.u4 = u;
            acc4[t] = __builtin_amdgcn_mfma_f32_16x16x32_bf16(wh[s],  cv.v8, acc4[t], 0, 0, 0);
            acc4[t] = __builtin_amdgcn_mfma_f32_16x16x32_bf16(wlo[s], cv.v8, acc4[t], 0, 0, 0);
        }
    }

    int fb = (ft << 4) + quad * 4;
    float4 bv = *(const float4*)(bias + fb);
#pragma unroll
    for (int t = 0; t < 4; ++t) {
        int node = node0 + (ntb + t) * 16 + lm;
        if (node >= N) continue;
        float r0 = acc4[t][0] + bv.x;
        float r1 = acc4[t][1] + bv.y;
        float r2 = acc4[t][2] + bv.z;
        float r3 = acc4[t][3] + bv.w;
        if (relu) {
            r0 = fmaxf(r0, 0.f); r1 = fmaxf(r1, 0.f);
            r2 = fmaxf(r2, 0.f); r3 = fmaxf(r3, 0.f);
        }
        if (outf) *(float4*)(outf + (long long)node * D + fb) = make_float4(r0, r1, r2, r3);
        if (outb) *(uint2*)(outb + (long long)node * 32 + (fb >> 1)) =
                      make_uint2(pack_bf(r0, r1), pack_bf(r2, r3));
    }
}

extern "C" void kernel_launch(void* const* d_in, const int* in_sizes, int n_in,
                              void* d_out, int out_size, void* d_ws, size_t ws_size,
                              hipStream_t stream) {
    const float* x   = (const float*)d_in[0];
    const int* ei    = (const int*)d_in[1];
    const float* W1l = (const float*)d_in[2];
    const float* W1r = (const float*)d_in[3];
    const float* b1  = (const float*)d_in[4];
    const float* W2l = (const float*)d_in[5];
    const float* W2r = (const float*)d_in[6];
    const float* b2  = (const float*)d_in[7];

    const int E = in_sizes[1] / 2;
    const int N = in_sizes[0] / D;     // requires N <= 102400 (17-bit src, NBK2_MAX)
    const int* src  = ei;
    const int* dstp = ei + E;
    const int NBK  = (N + BNODES - 1) >> BSHIFT;   // 782 for N=100k
    const int NBK2 = NBK << 3;                     // 6256 (bucket x srctile) regions
    const int G1 = 64;                             // big chunks -> coalesced region runs
    const int CE = (E + G1 - 1) / G1;

    char* ws = (char*)d_ws;
    size_t off = 0;
    auto alloc = [&](size_t bytes) { void* p = ws + off; off = (off + bytes + 255) & ~(size_t)255; return p; };
    int* cnt2           = (int*)alloc((size_t)NBK2 * 4);
    unsigned int* pairs = (unsigned int*)alloc(((size_t)NBK2 << SUBSH) * 4);  // 25.6MB
    unsigned int* xb    = (unsigned int*)alloc((size_t)N * 32 * 4);  // bf16 x
    unsigned int* hb    = (unsigned int*)alloc((size_t)N * 32 * 4);  // bf16 h

    float* out = (float*)d_out;

    // ---- cast features to bf16 (+ zero region counters) ----
    cast_kernel<<<2048, 256, 0, stream>>>((const float4*)x, (uint2*)xb, N * 16, cnt2, NBK2);

    // ---- single-pass (bucket, srctile) scatter; no scan, no csr sort ----
    binscatter_kernel<<<G1, 512, 0, stream>>>(src, dstp, cnt2, pairs, E, NBK2, CE);

    // ---- layer 1: edge-streaming aggregate + MFMA linear -> bf16 h ----
    stream_layer_kernel<<<NBK, 512, 0, stream>>>(xb, pairs, cnt2, W1l, W1r, b1,
                                                 nullptr, hb, N, 1);
    // ---- layer 2: edge-streaming aggregate + MFMA linear -> fp32 out ----
    stream_layer_kernel<<<NBK, 512, 0, stream>>>(hb, pairs, cnt2, W2l, W2r, b2,
                                                 out, nullptr, N, 0);
}

// Round 7
// 232.818 us; speedup vs baseline: 7.5258x; 7.5258x over previous
//
#include <hip/hip_runtime.h>

#define D 64
#define BSHIFT 8              // 256 nodes per bucket
#define BNODES (1 << BSHIFT)
#define NBK_MAX 512           // supports N up to 131072
#define CAPSH 13              // 8192-edge capacity per bucket region (mean 4096, +64 sigma; +padding <= 768)

typedef __attribute__((ext_vector_type(8))) short bf16x8;
typedef __attribute__((ext_vector_type(4))) float f32x4;

// ---------- bf16 helpers (bit-exact RNE pack, shift-based unpack) ----------
__device__ __forceinline__ unsigned int f2bf_rne(float f) {
    unsigned int b = __float_as_uint(f);
    return (b + 0x7fffu + ((b >> 16) & 1u)) >> 16;
}
__device__ __forceinline__ unsigned int pack_bf(float lo, float hi) {
    return f2bf_rne(lo) | (f2bf_rne(hi) << 16);
}
__device__ __forceinline__ float bflo(unsigned int u) { return __uint_as_float(u << 16); }
__device__ __forceinline__ float bfhi(unsigned int u) { return __uint_as_float(u & 0xffff0000u); }

// ---------- cast fp32 features -> packed bf16 (2 feats per uint); also zeroes cnt ----------
__global__ void cast_kernel(const float4* __restrict__ xin, uint2* __restrict__ xb, int n4,
                            int* __restrict__ cnt, int nz) {
    int gid = blockIdx.x * blockDim.x + threadIdx.x;
    if (gid < nz) cnt[gid] = 0;
    int stride = gridDim.x * blockDim.x;
    for (int i = gid; i < n4; i += stride) {
        float4 v = xin[i];
        uint2 o;
        o.x = pack_bf(v.x, v.y);
        o.y = pack_bf(v.z, v.w);
        xb[i] = o;
    }
}

// ---------- single-pass bucket scatter: (src | dst_low<<17) into CAP-strided regions ----------
// Per-block LDS histogram of its edge chunk, ONE global atomicAdd per (block,bucket) to
// reserve a run inside bucket k's region [k<<CAPSH, ...), then dense scatter.
// G1=128 blocks -> ~32-edge (128B) runs per (block,bucket) for better write coalescing.
__global__ __launch_bounds__(512) void binscatter_kernel(
    const int* __restrict__ src, const int* __restrict__ dst,
    int* __restrict__ cnt, unsigned int* __restrict__ pairs,
    int E, int NBK, int CE) {
    __shared__ int lh[NBK_MAX];
    __shared__ int lbase[NBK_MAX];
    for (int k = threadIdx.x; k < NBK; k += 512) lh[k] = 0;
    __syncthreads();
    int b = blockIdx.x;
    int beg = b * CE, end = min(beg + CE, E);
    for (int e = beg + threadIdx.x; e < end; e += 512)
        atomicAdd(&lh[dst[e] >> BSHIFT], 1);
    __syncthreads();
    for (int k = threadIdx.x; k < NBK; k += 512) {
        int c = lh[k];
        if (c) lbase[k] = (k << CAPSH) + atomicAdd(&cnt[k], c);
        lh[k] = 0;
    }
    __syncthreads();
    for (int e = beg + threadIdx.x; e < end; e += 512) {
        int d = dst[e];
        int k = d >> BSHIFT;
        int r = atomicAdd(&lh[k], 1);
        pairs[lbase[k] + r] = (unsigned int)src[e] | ((unsigned int)(d & (BNODES - 1)) << 17);
    }
}

// ---------- one workgroup per bucket -> per-node (beg,end) int2 + dst-sorted csr ----------
// The bucket's records are staged into LDS ONCE (single global read); hist and the
// sorting scatter then run against LDS. Node list bases are padded to 4-record
// alignment so the gather can load indices as one aligned int4 (dwordx4).
__global__ __launch_bounds__(256) void csr_build_kernel(
    const unsigned int* __restrict__ pairs, const int* __restrict__ cnt,
    int2* __restrict__ rowpair, int* __restrict__ csr, int N, int NBK) {
    __shared__ unsigned int spr[1 << CAPSH];   // 32 KB record stage
    __shared__ int lcnt[BNODES];
    __shared__ int s[256];
    int k = blockIdx.x;
    int tid = threadIdx.x;
    int node0 = k << BSHIFT;
    int nnodes = min(BNODES, N - node0);
    int rbeg = k << CAPSH;
    int cntk = cnt[k];

    for (int j = tid; j < BNODES; j += 256) lcnt[j] = 0;
    __syncthreads();
    for (int i = tid; i < cntk; i += 256) {        // coalesced single read + LDS stage + hist
        unsigned int rec = pairs[rbeg + i];
        spr[i] = rec;
        atomicAdd(&lcnt[rec >> 17], 1);
    }
    __syncthreads();
    int v0 = lcnt[tid];                 // BNODES == 256 == blockDim: 1 node/thread
    int ps = (v0 + 3) & ~3;             // pad node base to 4-record alignment
    s[tid] = ps;
    __syncthreads();
    for (int off = 1; off < 256; off <<= 1) {
        int t = (tid >= off) ? s[tid - off] : 0;
        __syncthreads();
        s[tid] += t;
        __syncthreads();
    }
    int ebase = s[tid] - ps;            // exclusive prefix of padded degrees
    int p = rbeg + ebase;               // 4-aligned (rbeg aligned, all ps multiples of 4)
    if (tid < nnodes) rowpair[node0 + tid] = make_int2(p, p + v0);
    lcnt[tid] = p;                      // scatter cursor
    __syncthreads();
    for (int i = tid; i < cntk; i += 256) {
        unsigned int rec = spr[i];
        int j = rec >> 17;
        int pos = atomicAdd(&lcnt[j], 1);
        csr[pos] = (int)(rec & 0x1FFFFu);
    }
}

// ---------- fused layer: aggregate 64 nodes -> LDS (swizzled bf16) -> MFMA linear ----------
// Round-2/5 proven structure: 256 threads = 4 waves; wave w aggregates nodes [w*16,w*16+16)
// in two serial octets (8 lanes x uint4 per row, 4-deep unroll = 32 row-loads in flight
// per wave, scalar tail). Node bases are 4-aligned, so the 4 csr indices load as ONE
// aligned int4 (shortens the serial head of each iteration). Means land in an 8KB LDS
// tile, XOR-swizzled at uint4 granularity (granule = fl ^ (node&7)). MFMA: wave w computes
// f-tile w over 4 node-tiles via 16x16x32 bf16 MFMA with hi/lo-split weights (fp32-accurate).
__global__ __launch_bounds__(256) void fused_layer_kernel(
    const unsigned int* __restrict__ xin, const int2* __restrict__ rowpair,
    const int* __restrict__ csr,
    const float* __restrict__ Wl, const float* __restrict__ Wr,
    const float* __restrict__ bias,
    float* __restrict__ outf, unsigned int* __restrict__ outb, int N, int relu) {
    __shared__ uint4 smean[64][8];      // [local node][granule], swizzled

    int tid = threadIdx.x;
    int wave = tid >> 6;
    int lane = tid & 63;
    int node0 = blockIdx.x * 64;

    // ---- aggregation phase ----
    int q  = lane >> 3;                 // node within octet
    int fl = lane & 7;                  // uint4 granule within 128B row
    for (int o = 0; o < 2; ++o) {
        int nl = (wave << 4) + (o << 3) + q;      // local node 0..63
        int node = node0 + nl;
        bool valid = node < N;
        int beg = 0, end = 0;
        if (valid) { int2 be = rowpair[node]; beg = be.x; end = be.y; }
        float s0 = 0.f, s1 = 0.f, s2 = 0.f, s3 = 0.f;
        float s4 = 0.f, s5 = 0.f, s6 = 0.f, s7 = 0.f;
        int j = beg;
        for (; j + 4 <= end; j += 4) {
            int4 iv = *(const int4*)(csr + j);    // 4-aligned: one dwordx4
            uint4 u0 = *(const uint4*)(xin + iv.x * 32 + fl * 4);
            uint4 u1 = *(const uint4*)(xin + iv.y * 32 + fl * 4);
            uint4 u2 = *(const uint4*)(xin + iv.z * 32 + fl * 4);
            uint4 u3 = *(const uint4*)(xin + iv.w * 32 + fl * 4);
            s0 += bflo(u0.x) + bflo(u1.x) + bflo(u2.x) + bflo(u3.x);
            s1 += bfhi(u0.x) + bfhi(u1.x) + bfhi(u2.x) + bfhi(u3.x);
            s2 += bflo(u0.y) + bflo(u1.y) + bflo(u2.y) + bflo(u3.y);
            s3 += bfhi(u0.y) + bfhi(u1.y) + bfhi(u2.y) + bfhi(u3.y);
            s4 += bflo(u0.z) + bflo(u1.z) + bflo(u2.z) + bflo(u3.z);
            s5 += bfhi(u0.z) + bfhi(u1.z) + bfhi(u2.z) + bfhi(u3.z);
            s6 += bflo(u0.w) + bflo(u1.w) + bflo(u2.w) + bflo(u3.w);
            s7 += bfhi(u0.w) + bfhi(u1.w) + bfhi(u2.w) + bfhi(u3.w);
        }
        for (; j < end; ++j) {
            uint4 u = *(const uint4*)(xin + csr[j] * 32 + fl * 4);
            s0 += bflo(u.x); s1 += bfhi(u.x);
            s2 += bflo(u.y); s3 += bfhi(u.y);
            s4 += bflo(u.z); s5 += bfhi(u.z);
            s6 += bflo(u.w); s7 += bfhi(u.w);
        }
        float inv = valid ? 1.0f / fmaxf((float)(end - beg), 1.0f) : 0.f;
        uint4 ov;
        ov.x = pack_bf(s0 * inv, s1 * inv);
        ov.y = pack_bf(s2 * inv, s3 * inv);
        ov.z = pack_bf(s4 * inv, s5 * inv);
        ov.w = pack_bf(s6 * inv, s7 * inv);
        smean[nl][fl ^ (nl & 7)] = ov;   // invalid nodes write zeros (inv=0)
    }

    // ---- weight fragments (overlap load latency with barrier wait) ----
    int lm   = lane & 15;
    int quad = lane >> 4;
    int f_a  = (wave << 4) + lm;
    bf16x8 wh[4], wlo[4];
#pragma unroll
    for (int s = 0; s < 4; ++s) {
        int k8 = s * 32 + quad * 8;
        const float* Wsrc = (k8 < 64) ? Wl : Wr;
        const float* p = Wsrc + f_a * 64 + (k8 & 63);
        float4 w0 = *(const float4*)p;
        float4 w1 = *(const float4*)(p + 4);
        float w[8] = {w0.x, w0.y, w0.z, w0.w, w1.x, w1.y, w1.z, w1.w};
        bf16x8 h, l;
#pragma unroll
        for (int jj = 0; jj < 8; ++jj) {
            unsigned int hb = f2bf_rne(w[jj]);
            float hf = __uint_as_float(hb << 16);
            unsigned int lb = f2bf_rne(w[jj] - hf);
            h[jj] = (short)hb;
            l[jj] = (short)lb;
        }
        wh[s] = h;
        wlo[s] = l;
    }

    __syncthreads();

    // ---- MFMA phase: out[f][node] tiles; K = [mean(64) ; x(64)] ----
    f32x4 acc[4];
#pragma unroll
    for (int nt = 0; nt < 4; ++nt) acc[nt] = (f32x4){0.f, 0.f, 0.f, 0.f};

#pragma unroll
    for (int nt = 0; nt < 4; ++nt) {
        int nl = nt * 16 + lm;
        int node = node0 + nl;
        bool v = node < N;
        const unsigned int* xrow = xin + (long long)node * 32;
#pragma unroll
        for (int s = 0; s < 2; ++s) {            // mean fragments from LDS
            union { uint4 u4; bf16x8 v8; } cv;
            cv.u4 = smean[nl][(s * 4 + quad) ^ (lm & 7)];
            acc[nt] = __builtin_amdgcn_mfma_f32_16x16x32_bf16(wh[s],  cv.v8, acc[nt], 0, 0, 0);
            acc[nt] = __builtin_amdgcn_mfma_f32_16x16x32_bf16(wlo[s], cv.v8, acc[nt], 0, 0, 0);
        }
#pragma unroll
        for (int s = 2; s < 4; ++s) {            // self fragments from global
            uint4 u = make_uint4(0u, 0u, 0u, 0u);
            if (v) u = *(const uint4*)(xrow + ((s & 1) << 4) + (quad << 2));
            union { uint4 u4; bf16x8 v8; } cv;
            cv.u4 = u;
            acc[nt] = __builtin_amdgcn_mfma_f32_16x16x32_bf16(wh[s],  cv.v8, acc[nt], 0, 0, 0);
            acc[nt] = __builtin_amdgcn_mfma_f32_16x16x32_bf16(wlo[s], cv.v8, acc[nt], 0, 0, 0);
        }
    }

    int fb = (wave << 4) + quad * 4;
    float4 bv = *(const float4*)(bias + fb);
#pragma unroll
    for (int nt = 0; nt < 4; ++nt) {
        int node = node0 + nt * 16 + lm;
        if (node >= N) continue;
        float r0 = acc[nt][0] + bv.x;
        float r1 = acc[nt][1] + bv.y;
        float r2 = acc[nt][2] + bv.z;
        float r3 = acc[nt][3] + bv.w;
        if (relu) {
            r0 = fmaxf(r0, 0.f); r1 = fmaxf(r1, 0.f);
            r2 = fmaxf(r2, 0.f); r3 = fmaxf(r3, 0.f);
        }
        if (outf) *(float4*)(outf + (long long)node * D + fb) = make_float4(r0, r1, r2, r3);
        if (outb) *(uint2*)(outb + (long long)node * 32 + (fb >> 1)) =
                      make_uint2(pack_bf(r0, r1), pack_bf(r2, r3));
    }
}

extern "C" void kernel_launch(void* const* d_in, const int* in_sizes, int n_in,
                              void* d_out, int out_size, void* d_ws, size_t ws_size,
                              hipStream_t stream) {
    const float* x   = (const float*)d_in[0];
    const int* ei    = (const int*)d_in[1];
    const float* W1l = (const float*)d_in[2];
    const float* W1r = (const float*)d_in[3];
    const float* b1  = (const float*)d_in[4];
    const float* W2l = (const float*)d_in[5];
    const float* W2r = (const float*)d_in[6];
    const float* b2  = (const float*)d_in[7];

    const int E = in_sizes[1] / 2;
    const int N = in_sizes[0] / D;     // requires N <= 131072 (17-bit packing)
    const int* src  = ei;
    const int* dstp = ei + E;
    const int NBK = (N + BNODES - 1) >> BSHIFT;   // 391 for N=100k
    const int G1 = 128;                           // ~32-edge runs per (block,bucket)
    const int CE = (E + G1 - 1) / G1;

    char* ws = (char*)d_ws;
    size_t off = 0;
    auto alloc = [&](size_t bytes) { void* p = ws + off; off = (off + bytes + 255) & ~(size_t)255; return p; };
    int* cnt            = (int*)alloc((size_t)NBK * 4);
    int2* rowpair       = (int2*)alloc((size_t)N * 8);
    unsigned int* pairs = (unsigned int*)alloc(((size_t)NBK << CAPSH) * 4);
    int* csr            = (int*)alloc(((size_t)NBK << CAPSH) * 4);
    unsigned int* xb    = (unsigned int*)alloc((size_t)N * 32 * 4);  // bf16 x
    unsigned int* hb    = (unsigned int*)alloc((size_t)N * 32 * 4);  // bf16 h

    float* out = (float*)d_out;

    // ---- cast features to bf16 (+ zero bucket counters) ----
    cast_kernel<<<2048, 256, 0, stream>>>((const float4*)x, (uint2*)xb, N * 16, cnt, NBK);

    // ---- CSR build: single-pass bucket scatter + LDS-staged per-bucket sort ----
    binscatter_kernel<<<G1, 512, 0, stream>>>(src, dstp, cnt, pairs, E, NBK, CE);
    csr_build_kernel<<<NBK, 256, 0, stream>>>(pairs, cnt, rowpair, csr, N, NBK);

    const int linGrid = (N + 63) / 64;

    // ---- layer 1: fused gather-mean + MFMA linear -> bf16 h ----
    fused_layer_kernel<<<linGrid, 256, 0, stream>>>(xb, rowpair, csr, W1l, W1r, b1,
                                                    nullptr, hb, N, 1);
    // ---- layer 2: fused gather-mean + MFMA linear -> fp32 out ----
    fused_layer_kernel<<<linGrid, 256, 0, stream>>>(hb, rowpair, csr, W2l, W2r, b2,
                                                    out, nullptr, N, 0);
}